// Round 14
// baseline (34020.596 us; speedup 1.0000x reference)
//
#include <hip/hip_runtime.h>

// Problem sizes (fixed by reference)
#define BB 32
#define TT 512
#define DD 512
#define HH 512
#define LL 4
#define HB (HH * BB)           // 16384
#define NWG 256                // 32 per XCD; exactly 1 WG/CU
#define TPB 256

// ws: data floats then flag/counter slots (memset to 0 by host each call)
#define STATE_FLOATS (LL * 2 * HB)              // 131072
#define GATE_FLOATS  (3 * LL * HB)              // 196608
#define DATA_FLOATS  (STATE_FLOATS + GATE_FLOATS)
#define FLAG_STRIDE  64                          // 256 B per counter slot
#define NFLAG        209                         // keep prior ws footprint
#define FLAGS_BYTES  ((unsigned long long)NFLAG * FLAG_STRIDE * 4ull)
#define WS_NEED_BYTES ((unsigned long long)DATA_FLOATS * 4ull + FLAGS_BYTES)

// LDS: resident weights + double-buffered input chunks (R6-proven).
#define KC    64                      // k per chunk
#define NCH   (HH / KC)               // 8 chunks per GEMV
#define IBR   68                      // input buffer row pitch (floats)
#define IBF   (BB * IBR)              // 2176 floats per chunk buffer
#define WLDS  32768                   // weight region (floats)
#define LDS_BYTES ((WLDS + 2 * IBF) * 4)   // 148480 <= 163840

// ---- self-timed dataflow (R13 structure), R14: flush-based publication ----
// R13 post-mortem: period pinned at ~23us/step across 5 structural variants;
// WRITE_SIZE = 2.13GB vs 557MB logical published data (3.8x amplification).
// Cause: pub_store wrote 4B/instruction -> 16B-useful-per-64B-line at TCC,
// and every small write-through transaction was ack'd inside wg_post's
// s_waitcnt(0) — an unmodeled multi-us term on EVERY hop, invariant across
// R11/R12/R13. Fix = R0's correctness-proven flush pattern:
//   producers: PLAIN coalesced float4 stores (full-line, L2-speed) ->
//   wg_post: __threadfence() (buffer_wbl2: L2 dirty lines -> IC) + barrier +
//   atomicAdd. Consumers unchanged (acquire-fence inv -> IC-fresh reads).
// Counters/layer-step: done_A = z(16)+r(16)+hU(16) = 48; done_B = 16.
// Deps per step t:
//   ZR/hU(i,t): U-side needs done_B[i-1] >= 16(t+1)  (i=0 reads x, no wait)
//               W-side / stores need done_B[i] >= 16t (prev ready + slot ack)
//   B(i,t): GEMV+epilogue need done_A[i] >= 48(t+1) (all gates; implies prow)
//           state store needs done_A[i+1] >= 48t (slot readers done) [i<3]
// R9 (kept): r-WGs store rp = sigmoid(a)*prev into rbuf; B stages ONE stream.
// R10 (kept): 32-col GEMVs use ksc=tid&7, cq=(tid>>3)&7, bq=tid>>6 (8 rows).
// R13 (kept): hU as 16x32-col WGs; staging prefetch depth 2.
// R8 lesson: tid0-only, register-dead, single-line, acquire-load wg_wait is
// load-bearing — untouched.
#define DONE_A(f, i) ((f) + (i) * FLAG_STRIDE)
#define DONE_B(f, i) ((f) + (8 + (i)) * FLAG_STRIDE)
#define SPIN_CAP (1 << 22)     // ~1.5 s worst case, then free-run (no hang)

__device__ __forceinline__ void wg_wait(int* cnt, int target, int& dead) {
    if (threadIdx.x == 0 && !dead) {
        int spins = 0;
        while (__hip_atomic_load(cnt, __ATOMIC_RELAXED,
                                 __HIP_MEMORY_SCOPE_AGENT) < target) {
            __builtin_amdgcn_s_sleep(2);
            if (++spins > SPIN_CAP) { dead = 1; break; }
        }
        // acquire: invalidate L1/L2 so subsequent plain loads see IC data
        (void)__hip_atomic_load(cnt, __ATOMIC_ACQUIRE,
                                __HIP_MEMORY_SCOPE_AGENT);
    }
    __syncthreads();
}

__device__ __forceinline__ void wg_post(int* cnt) {
    // R14: publish plain stores via ONE bulk L2 writeback (R0-proven),
    // replacing per-store write-through acks.
    __threadfence();                 // waitcnt + buffer_wbl2 + drain
    __syncthreads();                 // all threads' stores flushed
    if (threadIdx.x == 0)
        atomicAdd(cnt, 1);           // device-scope, IC-level
}

__device__ __forceinline__ float sigf(float v) {
    return 1.0f / (1.0f + __expf(-v));
}

// 32-fmaf tile (8 rows x 4 cols) on one weight float4
#define FMA32(WV, E0, E1, E2, E3, E4, E5, E6, E7)                           \
    acc[0][0] = fmaf(E0, WV.x, acc[0][0]); acc[0][1] = fmaf(E0, WV.y, acc[0][1]); \
    acc[0][2] = fmaf(E0, WV.z, acc[0][2]); acc[0][3] = fmaf(E0, WV.w, acc[0][3]); \
    acc[1][0] = fmaf(E1, WV.x, acc[1][0]); acc[1][1] = fmaf(E1, WV.y, acc[1][1]); \
    acc[1][2] = fmaf(E1, WV.z, acc[1][2]); acc[1][3] = fmaf(E1, WV.w, acc[1][3]); \
    acc[2][0] = fmaf(E2, WV.x, acc[2][0]); acc[2][1] = fmaf(E2, WV.y, acc[2][1]); \
    acc[2][2] = fmaf(E2, WV.z, acc[2][2]); acc[2][3] = fmaf(E2, WV.w, acc[2][3]); \
    acc[3][0] = fmaf(E3, WV.x, acc[3][0]); acc[3][1] = fmaf(E3, WV.y, acc[3][1]); \
    acc[3][2] = fmaf(E3, WV.z, acc[3][2]); acc[3][3] = fmaf(E3, WV.w, acc[3][3]); \
    acc[4][0] = fmaf(E4, WV.x, acc[4][0]); acc[4][1] = fmaf(E4, WV.y, acc[4][1]); \
    acc[4][2] = fmaf(E4, WV.z, acc[4][2]); acc[4][3] = fmaf(E4, WV.w, acc[4][3]); \
    acc[5][0] = fmaf(E5, WV.x, acc[5][0]); acc[5][1] = fmaf(E5, WV.y, acc[5][1]); \
    acc[5][2] = fmaf(E5, WV.z, acc[5][2]); acc[5][3] = fmaf(E5, WV.w, acc[5][3]); \
    acc[6][0] = fmaf(E6, WV.x, acc[6][0]); acc[6][1] = fmaf(E6, WV.y, acc[6][1]); \
    acc[6][2] = fmaf(E6, WV.z, acc[6][2]); acc[6][3] = fmaf(E6, WV.w, acc[6][3]); \
    acc[7][0] = fmaf(E7, WV.x, acc[7][0]); acc[7][1] = fmaf(E7, WV.y, acc[7][1]); \
    acc[7][2] = fmaf(E7, WV.z, acc[7][2]); acc[7][3] = fmaf(E7, WV.w, acc[7][3])

// One GEMV chunk for the 8-row map (reads rb at rows bq*8..+7, k ksc*8+kk*4+j)
#define CHUNK32(RB, WPC)                                                     \
    {                                                                        \
        const float* rbp = (RB) + (bq * 8) * IBR + ksc * 8;                  \
        _Pragma("unroll")                                                    \
        for (int kk = 0; kk < 2; ++kk) {                                     \
            float4 x0 = *(const float4*)&rbp[0 * IBR + kk * 4];              \
            float4 x1 = *(const float4*)&rbp[1 * IBR + kk * 4];              \
            float4 x2 = *(const float4*)&rbp[2 * IBR + kk * 4];              \
            float4 x3 = *(const float4*)&rbp[3 * IBR + kk * 4];              \
            float4 x4 = *(const float4*)&rbp[4 * IBR + kk * 4];              \
            float4 x5 = *(const float4*)&rbp[5 * IBR + kk * 4];              \
            float4 x6 = *(const float4*)&rbp[6 * IBR + kk * 4];              \
            float4 x7 = *(const float4*)&rbp[7 * IBR + kk * 4];              \
            _Pragma("unroll")                                                \
            for (int j = 0; j < 4; ++j) {                                    \
                float4 wv = *(const float4*)&(WPC)[(kk * 4 + j) * 32];       \
                FMA32(wv, (&x0.x)[j], (&x1.x)[j], (&x2.x)[j], (&x3.x)[j],    \
                          (&x4.x)[j], (&x5.x)[j], (&x6.x)[j], (&x7.x)[j]);   \
            }                                                                \
        }                                                                    \
    }

// Reduce over ksc octet + compile-time 8-way row select (rule #20)
#define REDUCE_SELECT8()                                                     \
    _Pragma("unroll")                                                        \
    for (int i = 0; i < 8; ++i)                                              \
        _Pragma("unroll")                                                    \
        for (int j = 0; j < 4; ++j) {                                        \
            float v = acc[i][j];                                             \
            v += __shfl_xor(v, 1, 64);                                       \
            v += __shfl_xor(v, 2, 64);                                       \
            v += __shfl_xor(v, 4, 64);                                       \
            acc[i][j] = v;                                                   \
        }                                                                    \
    float s0, s1, s2, s3;                                                    \
    if      (ksc == 0) { s0 = acc[0][0]; s1 = acc[0][1]; s2 = acc[0][2]; s3 = acc[0][3]; } \
    else if (ksc == 1) { s0 = acc[1][0]; s1 = acc[1][1]; s2 = acc[1][2]; s3 = acc[1][3]; } \
    else if (ksc == 2) { s0 = acc[2][0]; s1 = acc[2][1]; s2 = acc[2][2]; s3 = acc[2][3]; } \
    else if (ksc == 3) { s0 = acc[3][0]; s1 = acc[3][1]; s2 = acc[3][2]; s3 = acc[3][3]; } \
    else if (ksc == 4) { s0 = acc[4][0]; s1 = acc[4][1]; s2 = acc[4][2]; s3 = acc[4][3]; } \
    else if (ksc == 5) { s0 = acc[5][0]; s1 = acc[5][1]; s2 = acc[5][2]; s3 = acc[5][3]; } \
    else if (ksc == 6) { s0 = acc[6][0]; s1 = acc[6][1]; s2 = acc[6][2]; s3 = acc[6][3]; } \
    else               { s0 = acc[7][0]; s1 = acc[7][1]; s2 = acc[7][2]; s3 = acc[7][3]; }

// Staged 8-chunk GEMV, 2-deep register prefetch (R13)
#define STAGED_GEMV32(SRC0, RSTR, WOFF)                                      \
    {                                                                        \
        const float* src = (SRC0);                                           \
        float4 a0 = *(const float4*)&src[0];                                 \
        float4 a1 = *(const float4*)&src[RSTR];                              \
        src += KC;                                                           \
        *(float4*)&ib0[sb * IBR + sk * 4]        = a0;                       \
        *(float4*)&ib0[(sb + 16) * IBR + sk * 4] = a1;                       \
        a0 = *(const float4*)&src[0]; a1 = *(const float4*)&src[RSTR];       \
        src += KC;                                                           \
        float4 b0 = *(const float4*)&src[0];                                 \
        float4 b1 = *(const float4*)&src[RSTR];                              \
        src += KC;                                                           \
        __syncthreads();                                                     \
        float *rb = ib0, *nb = ib1;                                          \
        const float* wp0 = lds + (WOFF) + (ksc * 64 + cq) * 4;               \
        for (int c = 0; c < NCH; ++c) {                                      \
            const float* wp = wp0 + c * (KC * 8 * 4);                        \
            CHUNK32(rb, wp);                                                 \
            if (c < NCH - 1) {                                               \
                *(float4*)&nb[sb * IBR + sk * 4]        = a0;                 \
                *(float4*)&nb[(sb + 16) * IBR + sk * 4] = a1;                 \
                a0 = b0; a1 = b1;                                            \
                if (c < NCH - 3) {                                           \
                    b0 = *(const float4*)&src[0];                            \
                    b1 = *(const float4*)&src[RSTR];                         \
                    src += KC;                                               \
                }                                                            \
            }                                                                \
            __syncthreads();                                                 \
            float* tp = rb; rb = nb; nb = tp;                                \
        }                                                                    \
    }

// WG roles (logical wg 0..255), TPB=256. Buffers b-major (slice[b*512+col]).
//   wg   0..127: ZR z/r. grp=wg>>4: i=grp>>1, g=grp&1; 32 cols col0=(wg&15)*32.
//                U@0, W@16384.
//   wg 128..191: hU. w2=wg-128: i=w2>>4; 32 cols col0=(w2&15)*32. U2@0.
//   wg 192..255: B.  w3=wg-192: i=w3>>4; 32 cols col0B=(w3&15)*32. W2@0.
// 32-col compute map (R10): ksc=tid&7, cq=(tid>>3)&7, bq=tid>>6 (8 rows).
// staging map: sb=tid>>4 (rows sb, sb+16), sk=tid&15.
// Epilogue stores are now PLAIN float4 (16B/lane; 8 cq lanes/row cover a
// contiguous 128B = full lines) — published by wg_post's threadfence.

__global__ __launch_bounds__(TPB) void gru_wave(
    const float* __restrict__ x,    // [B,T,D]
    const float* __restrict__ Wp,   // [L,3,H,H]
    const float* __restrict__ Up,   // [L,3,D,H]
    float* __restrict__ out,        // [B,T,H]
    float* __restrict__ ws)
{
    extern __shared__ float lds[];

    const int bid = blockIdx.x;
    const int wg  = (bid & 7) * 32 + (bid >> 3);   // XCD-contiguous logical id
    const int tid = threadIdx.x;
    const int sb  = tid >> 4;          // staging row (and row+16)
    const int sk  = tid & 15;          // staging float4 within 64-k row chunk

    float* state = ws;                         // [L][2][B][H]
    float* zbuf  = state + LL * 2 * HB;        // [L][B][H]
    float* rbuf  = zbuf + LL * HB;             // holds rp = r*prev (R9)
    float* hUbuf = rbuf + LL * HB;
    int*   flags = (int*)(ws + DATA_FLOATS);

    float* ib0 = lds + WLDS;
    float* ib1 = ib0 + IBF;

    const bool isZR = wg < 128;
    const bool isHU = (wg >= 128) && (wg < 192);

    int iA = 0, gA = 0, col0 = 0, iB = 0, col0B = 0;
    if (isZR) { int grp = wg >> 4; iA = grp >> 1; gA = grp & 1; col0 = (wg & 15) * 32; }
    else if (isHU) { int w2 = wg - 128; iA = w2 >> 4; col0 = (w2 & 15) * 32; }
    else { int w3 = wg - 192; iB = w3 >> 4; col0B = (w3 & 15) * 32; }

    // ---- one-time weight staging: straight row-major float4 copy ----
    if (isZR) {
        const float* Um = Up + (size_t)(iA * 3 + gA) * DD * HH + col0;
        const float* Wm = Wp + (size_t)(iA * 3 + gA) * HH * HH + col0;
        for (int u = tid; u < 4096; u += TPB) {      // u = k*8 + cq
            int k = u >> 3, cc = u & 7;
            *(float4*)&lds[u * 4]         = *(const float4*)&Um[(size_t)k * HH + cc * 4];
            *(float4*)&lds[16384 + u * 4] = *(const float4*)&Wm[(size_t)k * HH + cc * 4];
        }
    } else {
        const float* Mm = isHU ? (Up + (size_t)(iA * 3 + 2) * DD * HH + col0)
                               : (Wp + (size_t)(iB * 3 + 2) * HH * HH + col0B);
        for (int u = tid; u < 4096; u += TPB) {      // u = k*8 + cq
            int k = u >> 3, cc = u & 7;
            *(float4*)&lds[u * 4] = *(const float4*)&Mm[(size_t)k * HH + cc * 4];
        }
    }
    __syncthreads();

    int dead = 0;
    const int ksc = tid & 7, cq = (tid >> 3) & 7, bq = tid >> 6;

    if (isZR) {
        const int colq = col0 + cq * 4;
        const int brow = bq * 8 + ksc;           // this lane's output row
        float* dst = (gA == 0 ? zbuf : rbuf) + (size_t)iA * HB;
        int* cb_up = (iA > 0) ? DONE_B(flags, iA - 1) : nullptr;
        int* cb_my = DONE_B(flags, iA);
        int* c_my  = DONE_A(flags, iA);
        for (int t = 0; t < TT; ++t) {
            float acc[8][4] = {};
            // ================= U-half (staged, prefetch-2) =================
            if (cb_up) wg_wait(cb_up, 16 * (t + 1), dead);
            if (iA == 0) {
                STAGED_GEMV32(x + (size_t)sb * TT * DD + (size_t)t * DD + sk * 4,
                              (size_t)16 * TT * DD, 0);
            } else {
                STAGED_GEMV32(state + (size_t)((iA - 1) * 2 + (t & 1)) * HB + sb * HH + sk * 4,
                              (size_t)16 * HH, 0);
            }
            // ================= W-half =================
            wg_wait(cb_my, 16 * t, dead);
            STAGED_GEMV32(state + (size_t)(iA * 2 + ((t + 1) & 1)) * HB + sb * HH + sk * 4,
                          (size_t)16 * HH, 16384);
            // R9: r-gate threads pre-load their 4 prev values (hidden under
            // the shuffle reduce) to form rp = sigmoid(a)*prev at the store.
            float4 p4 = make_float4(0.f, 0.f, 0.f, 0.f);
            if (gA == 1) {
                const float* prowE = state + (size_t)(iA * 2 + ((t + 1) & 1)) * HB
                                   + (size_t)brow * HH + colq;
                p4 = *(const float4*)prowE;
            }
            REDUCE_SELECT8();
            float* drow = dst + (size_t)brow * HH + colq;
            if (gA == 0) {
                *(float4*)drow = make_float4(sigf(s0), sigf(s1),
                                             sigf(s2), sigf(s3));
            } else {
                // rp = sigmoid(a) * prev — same floats, same multiply order
                *(float4*)drow = make_float4(sigf(s0) * p4.x, sigf(s1) * p4.y,
                                             sigf(s2) * p4.z, sigf(s3) * p4.w);
            }
            wg_post(c_my);
        }
    } else if (isHU) {
        const int colq = col0 + cq * 4;
        const int brow = bq * 8 + ksc;
        float* hu = hUbuf + (size_t)iA * HB;
        int* cb_up = (iA > 0) ? DONE_B(flags, iA - 1) : nullptr;
        int* cb_my = DONE_B(flags, iA);
        int* c_my  = DONE_A(flags, iA);
        for (int t = 0; t < TT; ++t) {
            float acc[8][4] = {};
            if (cb_up) wg_wait(cb_up, 16 * (t + 1), dead);
            if (iA == 0) {
                STAGED_GEMV32(x + (size_t)sb * TT * DD + (size_t)t * DD + sk * 4,
                              (size_t)16 * TT * DD, 0);
            } else {
                STAGED_GEMV32(state + (size_t)((iA - 1) * 2 + (t & 1)) * HB + sb * HH + sk * 4,
                              (size_t)16 * HH, 0);
            }
            // store-ack (B consumed hU(t-1))
            wg_wait(cb_my, 16 * t, dead);
            REDUCE_SELECT8();
            float* drow = hu + (size_t)brow * HH + colq;
            *(float4*)drow = make_float4(s0, s1, s2, s3);
            wg_post(c_my);
        }
    } else {
        const int colq = col0B + cq * 4;
        const int brow = bq * 8 + ksc;
        const float* rbase = rbuf + (size_t)iB * HB;   // holds rp (R9)
        const float* hu    = hUbuf + (size_t)iB * HB;
        const float* zz    = zbuf + (size_t)iB * HB;
        int* c_my = DONE_B(flags, iB);
        for (int t = 0; t < TT; ++t) {
            // all gates of step t ready (z, rp, hU) — implies prow complete
            wg_wait(DONE_A(flags, iB), 48 * (t + 1), dead);
            const float* prow = state + (size_t)(iB * 2 + ((t + 1) & 1)) * HB;
            float acc[8][4] = {};
            STAGED_GEMV32(rbase + (size_t)sb * HH + sk * 4, (size_t)16 * HH, 0);
            // state(t-2) slot overwrite-ack: downstream A(i+1,t-1) done
            if (iB < 3) wg_wait(DONE_A(flags, iB + 1), 48 * t, dead);
            REDUCE_SELECT8();
            float* stNew = state + (size_t)(iB * 2 + (t & 1)) * HB;
            float4 hu4 = *(const float4*)&hu[(size_t)brow * HH + colq];
            float4 zz4 = *(const float4*)&zz[(size_t)brow * HH + colq];
            float4 pv4 = *(const float4*)&prow[(size_t)brow * HH + colq];
            float av[4] = {s0, s1, s2, s3};
            float4 o4;
            #pragma unroll
            for (int j = 0; j < 4; ++j) {
                float h  = tanhf(av[j] + (&hu4.x)[j]);
                float zg = (&zz4.x)[j];
                float s  = zg * ((&pv4.x)[j] - h) + h;   // (1-z)*h + z*prev
                (&o4.x)[j] = s;
            }
            *(float4*)&stNew[(size_t)brow * HH + colq] = o4;
            if (iB == LL - 1)
                *(float4*)&out[((size_t)brow * TT + t) * HH + colq] = o4;
            wg_post(c_my);
        }
    }
}

extern "C" void kernel_launch(void* const* d_in, const int* in_sizes, int n_in,
                              void* d_out, int out_size, void* d_ws, size_t ws_size,
                              hipStream_t stream) {
    const float* x  = (const float*)d_in[0];  // [32,512,512]
    const float* Wp = (const float*)d_in[1];  // [4,3,512,512]
    const float* Up = (const float*)d_in[2];  // [4,3,512,512]
    float* out = (float*)d_out;
    float* ws  = (float*)d_ws;

    // Sentinel 1: workspace too small -> absmax ~8.5e37
    if (ws_size < WS_NEED_BYTES) {
        hipMemsetAsync(d_out, 0x7e, (size_t)out_size * sizeof(float), stream);
        return;
    }

    // Host-side zero of state (t=0 prev) and counters each call (R1-proven).
    hipMemsetAsync(ws, 0, (size_t)STATE_FLOATS * sizeof(float), stream);
    hipMemsetAsync(ws + DATA_FLOATS, 0, FLAGS_BYTES, stream);

    hipLaunchKernelGGL(gru_wave, dim3(NWG), dim3(TPB), LDS_BYTES, stream,
                       x, Wp, Up, out, ws);
    // Sentinel 2: launch rejected -> absmax ~3.4e38
    hipError_t err = hipGetLastError();
    if (err != hipSuccess)
        hipMemsetAsync(d_out, 0x7f, (size_t)out_size * sizeof(float), stream);
}

// Round 15
// 11481.701 us; speedup vs baseline: 2.9630x; 2.9630x over previous
//
#include <hip/hip_runtime.h>

// Problem sizes (fixed by reference)
#define BB 32
#define TT 512
#define DD 512
#define HH 512
#define LL 4
#define HB (HH * BB)           // 16384
#define NWG 224                // 28 per XCD; 1 WG/CU (LDS-bound)
#define TPB 256

// ws: data floats then flag/counter slots (memset to 0 by host each call)
#define STATE_FLOATS (LL * 2 * HB)              // 131072
#define GATE_FLOATS  (3 * LL * HB)              // 196608
#define DATA_FLOATS  (STATE_FLOATS + GATE_FLOATS)
#define FLAG_STRIDE  64                          // 256 B per counter slot
#define NFLAG        209                         // keep prior ws footprint
#define FLAGS_BYTES  ((unsigned long long)NFLAG * FLAG_STRIDE * 4ull)
#define WS_NEED_BYTES ((unsigned long long)DATA_FLOATS * 4ull + FLAGS_BYTES)

// LDS: resident weights + double-buffered input chunks (R6-proven).
#define KC    64                      // k per chunk
#define NCH   (HH / KC)               // 8 chunks per GEMV
#define IBR   68                      // input buffer row pitch (floats)
#define IBF   (BB * IBR)              // 2176 floats per chunk buffer
#define WLDS  32768                   // weight region (floats)
#define LDS_BYTES ((WLDS + 2 * IBF) * 4)   // 148480 <= 163840

// ---- R10 configuration RESTORED (best verified: 11.62 ms) ----
// Session ledger: R11 late-bind (11.79), R12 rU-split (12.48), R13 hU-split+
// prefetch2 (11.83), R14 wbl2-flush publication (34.0 — full-L2 writeback per
// phase per WG is catastrophic; write-through pub_store is the cheap option).
// All post-R10 structural experiments null or negative -> restore R10.
// done_A[i]: +1 per A-WG (32 ZR + 8 hU = 40/layer) per completed step.
// done_B[i]: +1 per B-WG (16/layer) per completed step.
//   A(i,t): U-side needs done_B[i-1] >= 16(t+1)  (inp; i=0 reads x, no wait)
//           W-side + stores need done_B[i] >= 16t (prev ready + gate ack)
//   B(i,t): needs done_A[i] >= 40(t+1); state stores need done_A[i+1] >= 40t
// R9 (kept): r-WGs store rp = sigmoid(a)*prev into rbuf; B stages ONE stream.
// R10 (kept): 32-col GEMVs use ksc=tid&7, cq=(tid>>3)&7, bq=tid>>6 (8 rows):
//   24 ds_read_b128/thread/chunk, weight reads at the bank-bandwidth floor.
// R8 lesson: tid0-only, register-dead, single-line, acquire-load wg_wait is
// load-bearing — untouched.
#define DONE_A(f, i) ((f) + (i) * FLAG_STRIDE)
#define DONE_B(f, i) ((f) + (8 + (i)) * FLAG_STRIDE)
#define SPIN_CAP (1 << 22)     // ~1.5 s worst case, then free-run (no hang)

__device__ __forceinline__ void wg_wait(int* cnt, int target, int& dead) {
    if (threadIdx.x == 0 && !dead) {
        int spins = 0;
        while (__hip_atomic_load(cnt, __ATOMIC_RELAXED,
                                 __HIP_MEMORY_SCOPE_AGENT) < target) {
            __builtin_amdgcn_s_sleep(2);
            if (++spins > SPIN_CAP) { dead = 1; break; }
        }
        // acquire: invalidate L1/L2 so subsequent plain loads see IC data
        (void)__hip_atomic_load(cnt, __ATOMIC_ACQUIRE,
                                __HIP_MEMORY_SCOPE_AGENT);
    }
    __syncthreads();
}

__device__ __forceinline__ void wg_post(int* cnt) {
    asm volatile("" ::: "memory");
    __builtin_amdgcn_s_waitcnt(0);   // own stores ack'd at coherence point
    __syncthreads();                 // all threads drained
    if (threadIdx.x == 0)
        atomicAdd(cnt, 1);           // device-scope, IC-level
}

__device__ __forceinline__ void pub_store(float* p, float v) {
    __hip_atomic_store(p, v, __ATOMIC_RELAXED, __HIP_MEMORY_SCOPE_AGENT);
}
__device__ __forceinline__ float sigf(float v) {
    return 1.0f / (1.0f + __expf(-v));
}

// 32-fmaf tile (8 rows x 4 cols) on one weight float4
#define FMA32(WV, E0, E1, E2, E3, E4, E5, E6, E7)                           \
    acc[0][0] = fmaf(E0, WV.x, acc[0][0]); acc[0][1] = fmaf(E0, WV.y, acc[0][1]); \
    acc[0][2] = fmaf(E0, WV.z, acc[0][2]); acc[0][3] = fmaf(E0, WV.w, acc[0][3]); \
    acc[1][0] = fmaf(E1, WV.x, acc[1][0]); acc[1][1] = fmaf(E1, WV.y, acc[1][1]); \
    acc[1][2] = fmaf(E1, WV.z, acc[1][2]); acc[1][3] = fmaf(E1, WV.w, acc[1][3]); \
    acc[2][0] = fmaf(E2, WV.x, acc[2][0]); acc[2][1] = fmaf(E2, WV.y, acc[2][1]); \
    acc[2][2] = fmaf(E2, WV.z, acc[2][2]); acc[2][3] = fmaf(E2, WV.w, acc[2][3]); \
    acc[3][0] = fmaf(E3, WV.x, acc[3][0]); acc[3][1] = fmaf(E3, WV.y, acc[3][1]); \
    acc[3][2] = fmaf(E3, WV.z, acc[3][2]); acc[3][3] = fmaf(E3, WV.w, acc[3][3]); \
    acc[4][0] = fmaf(E4, WV.x, acc[4][0]); acc[4][1] = fmaf(E4, WV.y, acc[4][1]); \
    acc[4][2] = fmaf(E4, WV.z, acc[4][2]); acc[4][3] = fmaf(E4, WV.w, acc[4][3]); \
    acc[5][0] = fmaf(E5, WV.x, acc[5][0]); acc[5][1] = fmaf(E5, WV.y, acc[5][1]); \
    acc[5][2] = fmaf(E5, WV.z, acc[5][2]); acc[5][3] = fmaf(E5, WV.w, acc[5][3]); \
    acc[6][0] = fmaf(E6, WV.x, acc[6][0]); acc[6][1] = fmaf(E6, WV.y, acc[6][1]); \
    acc[6][2] = fmaf(E6, WV.z, acc[6][2]); acc[6][3] = fmaf(E6, WV.w, acc[6][3]); \
    acc[7][0] = fmaf(E7, WV.x, acc[7][0]); acc[7][1] = fmaf(E7, WV.y, acc[7][1]); \
    acc[7][2] = fmaf(E7, WV.z, acc[7][2]); acc[7][3] = fmaf(E7, WV.w, acc[7][3])

// One GEMV chunk for the 8-row map (reads rb at rows bq*8..+7, k ksc*8+kk*4+j)
#define CHUNK32(RB, WPC)                                                     \
    {                                                                        \
        const float* rbp = (RB) + (bq * 8) * IBR + ksc * 8;                  \
        _Pragma("unroll")                                                    \
        for (int kk = 0; kk < 2; ++kk) {                                     \
            float4 x0 = *(const float4*)&rbp[0 * IBR + kk * 4];              \
            float4 x1 = *(const float4*)&rbp[1 * IBR + kk * 4];              \
            float4 x2 = *(const float4*)&rbp[2 * IBR + kk * 4];              \
            float4 x3 = *(const float4*)&rbp[3 * IBR + kk * 4];              \
            float4 x4 = *(const float4*)&rbp[4 * IBR + kk * 4];              \
            float4 x5 = *(const float4*)&rbp[5 * IBR + kk * 4];              \
            float4 x6 = *(const float4*)&rbp[6 * IBR + kk * 4];              \
            float4 x7 = *(const float4*)&rbp[7 * IBR + kk * 4];              \
            _Pragma("unroll")                                                \
            for (int j = 0; j < 4; ++j) {                                    \
                float4 wv = *(const float4*)&(WPC)[(kk * 4 + j) * 32];       \
                FMA32(wv, (&x0.x)[j], (&x1.x)[j], (&x2.x)[j], (&x3.x)[j],    \
                          (&x4.x)[j], (&x5.x)[j], (&x6.x)[j], (&x7.x)[j]);   \
            }                                                                \
        }                                                                    \
    }

// Reduce over ksc octet + compile-time 8-way row select (rule #20)
#define REDUCE_SELECT8()                                                     \
    _Pragma("unroll")                                                        \
    for (int i = 0; i < 8; ++i)                                              \
        _Pragma("unroll")                                                    \
        for (int j = 0; j < 4; ++j) {                                        \
            float v = acc[i][j];                                             \
            v += __shfl_xor(v, 1, 64);                                       \
            v += __shfl_xor(v, 2, 64);                                       \
            v += __shfl_xor(v, 4, 64);                                       \
            acc[i][j] = v;                                                   \
        }                                                                    \
    float s0, s1, s2, s3;                                                    \
    if      (ksc == 0) { s0 = acc[0][0]; s1 = acc[0][1]; s2 = acc[0][2]; s3 = acc[0][3]; } \
    else if (ksc == 1) { s0 = acc[1][0]; s1 = acc[1][1]; s2 = acc[1][2]; s3 = acc[1][3]; } \
    else if (ksc == 2) { s0 = acc[2][0]; s1 = acc[2][1]; s2 = acc[2][2]; s3 = acc[2][3]; } \
    else if (ksc == 3) { s0 = acc[3][0]; s1 = acc[3][1]; s2 = acc[3][2]; s3 = acc[3][3]; } \
    else if (ksc == 4) { s0 = acc[4][0]; s1 = acc[4][1]; s2 = acc[4][2]; s3 = acc[4][3]; } \
    else if (ksc == 5) { s0 = acc[5][0]; s1 = acc[5][1]; s2 = acc[5][2]; s3 = acc[5][3]; } \
    else if (ksc == 6) { s0 = acc[6][0]; s1 = acc[6][1]; s2 = acc[6][2]; s3 = acc[6][3]; } \
    else               { s0 = acc[7][0]; s1 = acc[7][1]; s2 = acc[7][2]; s3 = acc[7][3]; }

// WG roles (logical wg 0..223), TPB=256. Buffers b-major (slice[b*512+col]).
//   wg   0..127: A z/r. grp=wg>>4: i=grp>>1, g=grp&1; 32 cols.
//   wg 128..159: A hU. i=(wg-128)>>3; 64 cols (R9 map).
//   wg 160..223: B. w3=wg-160: i=w3>>4; 32 cols col0B=(w3&15)*32.
// 32-col compute map (R10): ksc=tid&7, cq=(tid>>3)&7, bq=tid>>6 (8 rows).
// 32-col weights (linear): lds[(k*8+cq)*4..]; ZR: U at 0, W at 16384; B at 0.
// staging map: sb=tid>>4 (rows sb, sb+16), sk=tid&15.

__global__ __launch_bounds__(TPB) void gru_wave(
    const float* __restrict__ x,    // [B,T,D]
    const float* __restrict__ Wp,   // [L,3,H,H]
    const float* __restrict__ Up,   // [L,3,D,H]
    float* __restrict__ out,        // [B,T,H]
    float* __restrict__ ws)
{
    extern __shared__ float lds[];

    const int bid = blockIdx.x;
    const int wg  = (bid & 7) * 28 + (bid >> 3);   // XCD-contiguous logical id
    const int tid = threadIdx.x;
    const int sb  = tid >> 4;          // staging row (and row+16)
    const int sk  = tid & 15;          // staging float4 within 64-k row chunk

    float* state = ws;                         // [L][2][B][H]
    float* zbuf  = state + LL * 2 * HB;        // [L][B][H]
    float* rbuf  = zbuf + LL * HB;             // holds rp = r*prev (R9)
    float* hUbuf = rbuf + LL * HB;
    int*   flags = (int*)(ws + DATA_FLOATS);

    float* ib0 = lds + WLDS;
    float* ib1 = ib0 + IBF;

    const bool isZR = wg < 128;
    const bool isHU = (wg >= 128) && (wg < 160);

    int iA = 0, gA = 0, col0 = 0, iB = 0, col0B = 0;
    if (isZR) { int grp = wg >> 4; iA = grp >> 1; gA = grp & 1; col0 = (wg & 15) * 32; }
    else if (isHU) { int w2 = wg - 128; iA = w2 >> 3; col0 = (w2 & 7) * 64; }
    else { int w3 = wg - 160; iB = w3 >> 4; col0B = (w3 & 15) * 32; }

    // ---- one-time weight staging: straight row-major float4 copy ----
    if (isZR) {
        const float* Um = Up + (size_t)(iA * 3 + gA) * DD * HH + col0;
        const float* Wm = Wp + (size_t)(iA * 3 + gA) * HH * HH + col0;
        for (int u = tid; u < 4096; u += TPB) {      // u = k*8 + cq
            int k = u >> 3, cc = u & 7;
            *(float4*)&lds[u * 4]         = *(const float4*)&Um[(size_t)k * HH + cc * 4];
            *(float4*)&lds[16384 + u * 4] = *(const float4*)&Wm[(size_t)k * HH + cc * 4];
        }
    } else if (isHU) {
        const float* Mm = Up + (size_t)(iA * 3 + 2) * DD * HH + col0;
        for (int u = tid; u < 8192; u += TPB) {      // u = k*16 + cq
            int k = u >> 4, cc = u & 15;
            *(float4*)&lds[u * 4] = *(const float4*)&Mm[(size_t)k * HH + cc * 4];
        }
    } else {
        const float* Mm = Wp + (size_t)(iB * 3 + 2) * HH * HH + col0B;
        for (int u = tid; u < 4096; u += TPB) {      // u = k*8 + cq
            int k = u >> 3, cc = u & 7;
            *(float4*)&lds[u * 4] = *(const float4*)&Mm[(size_t)k * HH + cc * 4];
        }
    }
    __syncthreads();

    int dead = 0;

    if (isZR) {
        const int ksc = tid & 7, cq = (tid >> 3) & 7, bq = tid >> 6;
        const int colq = col0 + cq * 4;
        const int brow = bq * 8 + ksc;           // this lane's output row
        float* dst = (gA == 0 ? zbuf : rbuf) + (size_t)iA * HB;
        int* cb_up = (iA > 0) ? DONE_B(flags, iA - 1) : nullptr;
        int* cb_my = DONE_B(flags, iA);
        int* c_my  = DONE_A(flags, iA);
        for (int t = 0; t < TT; ++t) {
            float acc[8][4] = {};
            // ================= U-half (staged) =================
            if (cb_up) wg_wait(cb_up, 16 * (t + 1), dead);
            {
                const float* src; size_t rstr;
                if (iA == 0) {
                    src = x + (size_t)sb * TT * DD + (size_t)t * DD + sk * 4;
                    rstr = (size_t)16 * TT * DD;
                } else {
                    src = state + (size_t)((iA - 1) * 2 + (t & 1)) * HB + sb * HH + sk * 4;
                    rstr = (size_t)16 * HH;
                }
                float4 g0 = *(const float4*)&src[0];
                float4 g1 = *(const float4*)&src[rstr];
                src += KC;
                *(float4*)&ib0[sb * IBR + sk * 4]        = g0;
                *(float4*)&ib0[(sb + 16) * IBR + sk * 4] = g1;
                g0 = *(const float4*)&src[0]; g1 = *(const float4*)&src[rstr]; src += KC;
                __syncthreads();
                float *rb = ib0, *nb = ib1;
                const float* wp0 = lds + (ksc * 64 + cq) * 4;
                for (int c = 0; c < NCH; ++c) {
                    const float* wp = wp0 + c * (KC * 8 * 4);
                    CHUNK32(rb, wp);
                    if (c < NCH - 1) {
                        *(float4*)&nb[sb * IBR + sk * 4]        = g0;
                        *(float4*)&nb[(sb + 16) * IBR + sk * 4] = g1;
                        if (c < NCH - 2) {
                            g0 = *(const float4*)&src[0];
                            g1 = *(const float4*)&src[rstr];
                            src += KC;
                        }
                    }
                    __syncthreads();
                    float* tp = rb; rb = nb; nb = tp;
                }
            }
            // ================= W-half (staged) =================
            wg_wait(cb_my, 16 * t, dead);
            {
                const float* src = state + (size_t)(iA * 2 + ((t + 1) & 1)) * HB
                                 + sb * HH + sk * 4;
                const size_t rstr = (size_t)16 * HH;
                float4 g0 = *(const float4*)&src[0];
                float4 g1 = *(const float4*)&src[rstr];
                src += KC;
                *(float4*)&ib0[sb * IBR + sk * 4]        = g0;
                *(float4*)&ib0[(sb + 16) * IBR + sk * 4] = g1;
                g0 = *(const float4*)&src[0]; g1 = *(const float4*)&src[rstr]; src += KC;
                __syncthreads();
                float *rb = ib0, *nb = ib1;
                const float* wp0 = lds + 16384 + (ksc * 64 + cq) * 4;
                for (int c = 0; c < NCH; ++c) {
                    const float* wp = wp0 + c * (KC * 8 * 4);
                    CHUNK32(rb, wp);
                    if (c < NCH - 1) {
                        *(float4*)&nb[sb * IBR + sk * 4]        = g0;
                        *(float4*)&nb[(sb + 16) * IBR + sk * 4] = g1;
                        if (c < NCH - 2) {
                            g0 = *(const float4*)&src[0];
                            g1 = *(const float4*)&src[rstr];
                            src += KC;
                        }
                    }
                    __syncthreads();
                    float* tp = rb; rb = nb; nb = tp;
                }
            }
            // R9: r-gate threads pre-load their 4 prev values (hidden under
            // the shuffle reduce) to form rp = sigmoid(a)*prev at the store.
            float4 p4 = make_float4(0.f, 0.f, 0.f, 0.f);
            if (gA == 1) {
                const float* prowE = state + (size_t)(iA * 2 + ((t + 1) & 1)) * HB
                                   + (size_t)brow * HH + colq;
                p4 = *(const float4*)prowE;
            }
            REDUCE_SELECT8();
            float* drow = dst + (size_t)brow * HH + colq;
            if (gA == 0) {
                pub_store(&drow[0], sigf(s0));
                pub_store(&drow[1], sigf(s1));
                pub_store(&drow[2], sigf(s2));
                pub_store(&drow[3], sigf(s3));
            } else {
                // rp = sigmoid(a) * prev — same floats, same multiply order
                pub_store(&drow[0], sigf(s0) * p4.x);
                pub_store(&drow[1], sigf(s1) * p4.y);
                pub_store(&drow[2], sigf(s2) * p4.z);
                pub_store(&drow[3], sigf(s3) * p4.w);
            }
            wg_post(c_my);
        }
    } else if (isHU) {
        const int ks2 = tid & 1, cq = (tid >> 1) & 15, bq = tid >> 5;
        const int colq = col0 + cq * 4;
        float* hu = hUbuf + (size_t)iA * HB;
        int* cb_up = (iA > 0) ? DONE_B(flags, iA - 1) : nullptr;
        int* cb_my = DONE_B(flags, iA);
        int* c_my  = DONE_A(flags, iA);
        for (int t = 0; t < TT; ++t) {
            float acc[4][4] = {};
            if (cb_up) wg_wait(cb_up, 16 * (t + 1), dead);
            {
                const float* src; size_t rstr;
                if (iA == 0) {
                    src = x + (size_t)sb * TT * DD + (size_t)t * DD + sk * 4;
                    rstr = (size_t)16 * TT * DD;
                } else {
                    src = state + (size_t)((iA - 1) * 2 + (t & 1)) * HB + sb * HH + sk * 4;
                    rstr = (size_t)16 * HH;
                }
                float4 g0 = *(const float4*)&src[0];
                float4 g1 = *(const float4*)&src[rstr];
                src += KC;
                *(float4*)&ib0[sb * IBR + sk * 4]        = g0;
                *(float4*)&ib0[(sb + 16) * IBR + sk * 4] = g1;
                g0 = *(const float4*)&src[0]; g1 = *(const float4*)&src[rstr]; src += KC;
                __syncthreads();
                float *rb = ib0, *nb = ib1;
                const float* wp0 = lds + (ks2 * 32 * 16 + cq) * 4;
                for (int c = 0; c < NCH; ++c) {
                    const float* r0 = rb + (bq * 4 + 0) * IBR + ks2 * 32;
                    const float* r1 = rb + (bq * 4 + 1) * IBR + ks2 * 32;
                    const float* r2 = rb + (bq * 4 + 2) * IBR + ks2 * 32;
                    const float* r3 = rb + (bq * 4 + 3) * IBR + ks2 * 32;
                    const float* wp = wp0 + c * (KC * 16 * 4);
                    #pragma unroll
                    for (int kk = 0; kk < 8; ++kk) {
                        float4 x0 = *(const float4*)&r0[kk * 4];
                        float4 x1 = *(const float4*)&r1[kk * 4];
                        float4 x2 = *(const float4*)&r2[kk * 4];
                        float4 x3 = *(const float4*)&r3[kk * 4];
                        #pragma unroll
                        for (int j = 0; j < 4; ++j) {
                            float4 wv = *(const float4*)&wp[(kk * 4 + j) * 64];
                            float e0 = (&x0.x)[j], e1 = (&x1.x)[j];
                            float e2 = (&x2.x)[j], e3 = (&x3.x)[j];
                            acc[0][0] = fmaf(e0, wv.x, acc[0][0]); acc[0][1] = fmaf(e0, wv.y, acc[0][1]);
                            acc[0][2] = fmaf(e0, wv.z, acc[0][2]); acc[0][3] = fmaf(e0, wv.w, acc[0][3]);
                            acc[1][0] = fmaf(e1, wv.x, acc[1][0]); acc[1][1] = fmaf(e1, wv.y, acc[1][1]);
                            acc[1][2] = fmaf(e1, wv.z, acc[1][2]); acc[1][3] = fmaf(e1, wv.w, acc[1][3]);
                            acc[2][0] = fmaf(e2, wv.x, acc[2][0]); acc[2][1] = fmaf(e2, wv.y, acc[2][1]);
                            acc[2][2] = fmaf(e2, wv.z, acc[2][2]); acc[2][3] = fmaf(e2, wv.w, acc[2][3]);
                            acc[3][0] = fmaf(e3, wv.x, acc[3][0]); acc[3][1] = fmaf(e3, wv.y, acc[3][1]);
                            acc[3][2] = fmaf(e3, wv.z, acc[3][2]); acc[3][3] = fmaf(e3, wv.w, acc[3][3]);
                        }
                    }
                    if (c < NCH - 1) {
                        *(float4*)&nb[sb * IBR + sk * 4]        = g0;
                        *(float4*)&nb[(sb + 16) * IBR + sk * 4] = g1;
                        if (c < NCH - 2) {
                            g0 = *(const float4*)&src[0];
                            g1 = *(const float4*)&src[rstr];
                            src += KC;
                        }
                    }
                    __syncthreads();
                    float* tp = rb; rb = nb; nb = tp;
                }
            }
            // store-ack (B consumed hU(t-1)); then reduce over k-halves
            wg_wait(cb_my, 16 * t, dead);
            #pragma unroll
            for (int i = 0; i < 4; ++i)
                #pragma unroll
                for (int j = 0; j < 4; ++j) {
                    float v = acc[i][j];
                    v += __shfl_xor(v, 1, 64);
                    acc[i][j] = v;
                }
            float r0v[4], r1v[4];
            if (ks2 == 0) {
                r0v[0]=acc[0][0]; r0v[1]=acc[0][1]; r0v[2]=acc[0][2]; r0v[3]=acc[0][3];
                r1v[0]=acc[1][0]; r1v[1]=acc[1][1]; r1v[2]=acc[1][2]; r1v[3]=acc[1][3];
            } else {
                r0v[0]=acc[2][0]; r0v[1]=acc[2][1]; r0v[2]=acc[2][2]; r0v[3]=acc[2][3];
                r1v[0]=acc[3][0]; r1v[1]=acc[3][1]; r1v[2]=acc[3][2]; r1v[3]=acc[3][3];
            }
            const int b0 = bq * 4 + ks2 * 2;
            float* h0 = hu + (size_t)b0 * HH + colq;
            float* h1 = hu + (size_t)(b0 + 1) * HH + colq;
            pub_store(&h0[0], r0v[0]); pub_store(&h0[1], r0v[1]);
            pub_store(&h0[2], r0v[2]); pub_store(&h0[3], r0v[3]);
            pub_store(&h1[0], r1v[0]); pub_store(&h1[1], r1v[1]);
            pub_store(&h1[2], r1v[2]); pub_store(&h1[3], r1v[3]);
            wg_post(c_my);
        }
    } else {
        const int ksc = tid & 7, cq = (tid >> 3) & 7, bq = tid >> 6;
        const int colq = col0B + cq * 4;
        const int brow = bq * 8 + ksc;
        const float* rbase = rbuf + (size_t)iB * HB;   // holds rp (R9)
        const float* hu    = hUbuf + (size_t)iB * HB;
        const float* zz    = zbuf + (size_t)iB * HB;
        int* c_my = DONE_B(flags, iB);
        for (int t = 0; t < TT; ++t) {
            // all gates of step t ready (z, rp, hU) — implies prow complete
            wg_wait(DONE_A(flags, iB), 40 * (t + 1), dead);
            const float* prow = state + (size_t)(iB * 2 + ((t + 1) & 1)) * HB;
            float acc[8][4] = {};
            {
                // single staged stream — rbuf already holds rp = r*prev
                const float* src = rbase + (size_t)sb * HH + sk * 4;
                const size_t rstr = (size_t)16 * HH;
                float4 g0 = *(const float4*)&src[0];
                float4 g1 = *(const float4*)&src[rstr];
                src += KC;
                *(float4*)&ib0[sb * IBR + sk * 4]        = g0;
                *(float4*)&ib0[(sb + 16) * IBR + sk * 4] = g1;
                g0 = *(const float4*)&src[0]; g1 = *(const float4*)&src[rstr]; src += KC;
                __syncthreads();
                float *rb = ib0, *nb = ib1;
                const float* wp0 = lds + (ksc * 64 + cq) * 4;
                for (int c = 0; c < NCH; ++c) {
                    const float* wp = wp0 + c * (KC * 8 * 4);
                    CHUNK32(rb, wp);
                    if (c < NCH - 1) {
                        *(float4*)&nb[sb * IBR + sk * 4]        = g0;
                        *(float4*)&nb[(sb + 16) * IBR + sk * 4] = g1;
                        if (c < NCH - 2) {
                            g0 = *(const float4*)&src[0];
                            g1 = *(const float4*)&src[rstr];
                            src += KC;
                        }
                    }
                    __syncthreads();
                    float* tp = rb; rb = nb; nb = tp;
                }
            }
            // state(t-2) slot overwrite-ack: downstream A(i+1,t-1) done
            if (iB < 3) wg_wait(DONE_A(flags, iB + 1), 40 * t, dead);
            REDUCE_SELECT8();
            float* stNew = state + (size_t)(iB * 2 + (t & 1)) * HB;
            float4 hu4 = *(const float4*)&hu[(size_t)brow * HH + colq];
            float4 zz4 = *(const float4*)&zz[(size_t)brow * HH + colq];
            float4 pv4 = *(const float4*)&prow[(size_t)brow * HH + colq];
            float av[4] = {s0, s1, s2, s3};
            float4 o4;
            #pragma unroll
            for (int j = 0; j < 4; ++j) {
                float h  = tanhf(av[j] + (&hu4.x)[j]);
                float zg = (&zz4.x)[j];
                float s  = zg * ((&pv4.x)[j] - h) + h;   // (1-z)*h + z*prev
                pub_store(&stNew[(size_t)brow * HH + colq + j], s);
                (&o4.x)[j] = s;
            }
            if (iB == LL - 1)
                *(float4*)&out[((size_t)brow * TT + t) * HH + colq] = o4;
            wg_post(c_my);
        }
    }
}

extern "C" void kernel_launch(void* const* d_in, const int* in_sizes, int n_in,
                              void* d_out, int out_size, void* d_ws, size_t ws_size,
                              hipStream_t stream) {
    const float* x  = (const float*)d_in[0];  // [32,512,512]
    const float* Wp = (const float*)d_in[1];  // [4,3,512,512]
    const float* Up = (const float*)d_in[2];  // [4,3,512,512]
    float* out = (float*)d_out;
    float* ws  = (float*)d_ws;

    // Sentinel 1: workspace too small -> absmax ~8.5e37
    if (ws_size < WS_NEED_BYTES) {
        hipMemsetAsync(d_out, 0x7e, (size_t)out_size * sizeof(float), stream);
        return;
    }

    // Host-side zero of state (t=0 prev) and counters each call (R1-proven).
    hipMemsetAsync(ws, 0, (size_t)STATE_FLOATS * sizeof(float), stream);
    hipMemsetAsync(ws + DATA_FLOATS, 0, FLAGS_BYTES, stream);

    hipLaunchKernelGGL(gru_wave, dim3(NWG), dim3(TPB), LDS_BYTES, stream,
                       x, Wp, Up, out, ws);
    // Sentinel 2: launch rejected -> absmax ~3.4e38
    hipError_t err = hipGetLastError();
    if (err != hipSuccess)
        hipMemsetAsync(d_out, 0x7f, (size_t)out_size * sizeof(float), stream);
}